// Round 9
// baseline (458.362 us; speedup 1.0000x reference)
//
#include <hip/hip_runtime.h>
#include <math.h>
#include <cstdint>

#define B_ 4
#define C_ 384
#define V_ 8
#define H_ 181
#define W_ 360
#define HW_ (H_*W_)      // 65160
#define NP_ (B_*HW_)     // 260640
#define HP_ (H_+4)       // 185
#define WP_ (W_+4)       // 364

typedef float f32x2 __attribute__((ext_vector_type(2)));

// ------------------------------------------------------------------
// k_prep: fold biases; pair-interleaved weight tables.
// ------------------------------------------------------------------
__global__ void k_prep(const float* __restrict__ scale,
                       const float* __restrict__ bias,
                       const float* __restrict__ dwk,
                       const float* __restrict__ dwb,
                       const float* __restrict__ pw_w,
                       const float* __restrict__ pw_b,
                       const float* __restrict__ up_w,
                       float* __restrict__ vbias,
                       float* __restrict__ kswt2,
                       float* __restrict__ pwT2,
                       float* __restrict__ upT2) {
  __shared__ float sb[C_];
  int t = threadIdx.x;
  if (t < C_) {
    float ks = 0.f;
    float sc = scale[t];
    int pr = t >> 1, lo = t & 1;
#pragma unroll
    for (int k = 0; k < 9; ++k) {
      float kv = dwk[t * 9 + k];
      ks += kv;
      kswt2[pr * 18 + k * 2 + lo] = kv * sc;
    }
#pragma unroll
    for (int o = 0; o < 16; ++o) pwT2[pr * 32 + o * 2 + lo] = pw_w[o * C_ + t];
#pragma unroll
    for (int v = 0; v < 8; ++v) upT2[pr * 16 + v * 2 + lo] = up_w[t * V_ + v];
    sb[t] = bias[t] * ks + dwb[t];
  }
  __syncthreads();
  if (t < 16) {
    float acc = pw_b[t];
    for (int c = 0; c < C_; ++c) acc = fmaf(pw_w[t * C_ + c], sb[c], acc);
    vbias[t] = acc;
  }
}

// ------------------------------------------------------------------
// k_stats: LN mean/rstd per pixel + fused down-proj (raw x, 1x1 C->8)
// ------------------------------------------------------------------
__global__ __launch_bounds__(256) void k_stats(
    const float* __restrict__ x, const float* __restrict__ down_w,
    const float* __restrict__ down_b, float* __restrict__ meanv,
    float* __restrict__ rstdv, float* __restrict__ proj) {
  int p = blockIdx.x * 256 + threadIdx.x;
  if (p >= NP_) return;
  int b = p / HW_, hw = p - b * HW_;
  const float* xp = x + (size_t)b * C_ * HW_ + hw;

  float sA = 0.f, sB = 0.f, s2A = 0.f, s2B = 0.f;
  float apA[8], apB[8];
#pragma unroll
  for (int j = 0; j < 8; ++j) { apA[j] = 0.f; apB[j] = 0.f; }

#pragma unroll 4
  for (int c = 0; c < C_ / 2; ++c) {
    float v0 = xp[(size_t)c * HW_];
    float v1 = xp[(size_t)(c + C_ / 2) * HW_];
    sA += v0;
    sB += v1;
    s2A = fmaf(v0, v0, s2A);
    s2B = fmaf(v1, v1, s2B);
#pragma unroll
    for (int j = 0; j < 8; ++j) {
      apA[j] = fmaf(v0, down_w[j * C_ + c], apA[j]);
      apB[j] = fmaf(v1, down_w[j * C_ + c + C_ / 2], apB[j]);
    }
  }
  float m = (sA + sB) * (1.0f / C_);
  float var = fmaf(-m, m, (s2A + s2B) * (1.0f / C_));
  var = var < 0.f ? 0.f : var;
  meanv[p] = m;
  rstdv[p] = rsqrtf(var + 1e-5f);
#pragma unroll
  for (int j = 0; j < 8; ++j)
    proj[((size_t)b * 8 + j) * HW_ + hw] = apA[j] + apB[j] + down_b[j];
}

// ------------------------------------------------------------------
// k_vel: LN apply + geo-pad depthwise 3x3 + 1x1 (C->16) velocity.
// 4 autonomous waves/block (private LDS, 0 barriers), K-split x4
// (96 ch = 6 chunks per wave), pinned register prefetch, packed f32,
// fire-and-forget f32 atomics for the K-reduction.
// ------------------------------------------------------------------
#define BTW 16
#define BTH 16                      // 4 waves x 4 rows
#define WHW 18
#define WHH 6
#define WNH (WHW*WHH)               // 108
#define KP 8                        // channel pairs per chunk
#define KC (2*KP)                   // 16
#define CSPL 4
#define CPW (C_/CSPL)               // 96
#define NCH (CPW/KC)                // 6
#define NBX ((W_ + BTW - 1) / BTW)  // 23
#define NBY ((H_ + BTH - 1) / BTH)  // 12
#define NWG_VEL (NBX*NBY*B_*CSPL)   // 4416  (= 8 * 552, exact)

__device__ __forceinline__ int geo_off_w(int h0, int w0, int i) {
  int hy = i / WHW, hx = i - hy * WHW;
  int hh = h0 - 1 + hy;
  int ww = w0 - 1 + hx;
  int hs, sh = 0;
  if (hh < 0)        { hs = -1 - hh;         sh = 180; }
  else if (hh >= H_) { hs = 2 * H_ - 1 - hh; sh = 180; }
  else               { hs = hh; }
  int ws2 = ww + sh;
  ws2 = ((ws2 % W_) + W_) % W_;
  return hs * W_ + ws2;
}

__global__ __launch_bounds__(256) void k_vel(
    const float* __restrict__ x, const float* __restrict__ meanv,
    const float* __restrict__ rstdv, const float* __restrict__ kswt2,
    const float* __restrict__ pwT2, float* __restrict__ velA) {
  __shared__ f32x2 xn[4][KP][WNH];

  int tid = threadIdx.x;
  int wid = tid >> 6, lane = tid & 63;

  // bijective XCD swizzle (4416 % 8 == 0)
  int bid = blockIdx.x;
  int wg = (bid & 7) * (NWG_VEL / 8) + (bid >> 3);
  int bw = wg % NBX; wg /= NBX;
  int by = wg % NBY; wg /= NBY;
  int b  = wg % B_;
  int sl = wg / B_;
  int w0 = bw * BTW;
  int h0 = by * BTH + wid * 4;   // this wave's 4-row strip
  int cbase = sl * CPW;

  int i0 = lane, i1 = lane + 64;
  bool has1 = (i1 < WNH);  // lanes 0..43
  int o0 = geo_off_w(h0, w0, i0);
  int o1 = has1 ? geo_off_w(h0, w0, i1) : o0;

  size_t bHW = (size_t)b * HW_;
  float r0v = rstdv[bHW + o0];
  float n0v = -meanv[bHW + o0] * r0v;  // xn = x*r + n
  float r1v = rstdv[bHW + o1];
  float n1v = -meanv[bHW + o1] * r1v;
  f32x2 r0P = {r0v, r0v}, n0P = {n0v, n0v};
  f32x2 r1P = {r1v, r1v}, n1P = {n1v, n1v};

  const float* xb0 = x + ((size_t)b * C_ + cbase) * HW_ + o0;
  const float* xb1 = x + ((size_t)b * C_ + cbase) * HW_ + o1;

  f32x2 pf0[KP], pf1[KP];
#pragma unroll
  for (int k = 0; k < KP; ++k) {
    pf0[k].x = xb0[(size_t)(2 * k) * HW_];
    pf0[k].y = xb0[(size_t)(2 * k + 1) * HW_];
    pf1[k].x = xb1[(size_t)(2 * k) * HW_];
    pf1[k].y = xb1[(size_t)(2 * k + 1) * HW_];
  }

  int tx = lane & 15, ty = lane >> 4;
  f32x2 accP[16];
#pragma unroll
  for (int o = 0; o < 16; ++o) accP[o] = f32x2{0.f, 0.f};

  const f32x2* kk2 = (const f32x2*)kswt2;  // [pair*9 + tap]
  const f32x2* pw2 = (const f32x2*)pwT2;   // [pair*16 + o]
  f32x2 (*xw)[WNH] = xn[wid];              // this wave's private slice
  int pbase = cbase >> 1;                  // pair index base

#pragma unroll 1
  for (int chunk = 0; chunk < NCH - 1; ++chunk) {
    // ---- stage current chunk's normalized pairs into private LDS ----
#pragma unroll
    for (int k = 0; k < KP; ++k)
      xw[k][i0] = __builtin_elementwise_fma(pf0[k], r0P, n0P);
    if (has1) {
#pragma unroll
      for (int k = 0; k < KP; ++k)
        xw[k][i1] = __builtin_elementwise_fma(pf1[k], r1P, n1P);
    }

    // ---- issue next chunk's global loads ----
    {
      const float* xc0 = xb0 + (size_t)(chunk + 1) * KC * HW_;
      const float* xc1 = xb1 + (size_t)(chunk + 1) * KC * HW_;
#pragma unroll
      for (int k = 0; k < KP; ++k) {
        pf0[k].x = xc0[(size_t)(2 * k) * HW_];
        pf0[k].y = xc0[(size_t)(2 * k + 1) * HW_];
        pf1[k].x = xc1[(size_t)(2 * k) * HW_];
        pf1[k].y = xc1[(size_t)(2 * k + 1) * HW_];
      }
    }
    // pin: loads may not sink below; compute may not hoist above
    __builtin_amdgcn_sched_barrier(0);

    // ---- compute current chunk ----
    int pc0 = pbase + chunk * KP;
#pragma unroll
    for (int kp = 0; kp < KP; ++kp) {
      const f32x2* kk = kk2 + (size_t)(pc0 + kp) * 9;   // wave-uniform
      const f32x2* pw = pw2 + (size_t)(pc0 + kp) * 16;  // wave-uniform
      f32x2 aP = {0.f, 0.f};
#pragma unroll
      for (int dy = 0; dy < 3; ++dy)
#pragma unroll
        for (int dx = 0; dx < 3; ++dx)
          aP = __builtin_elementwise_fma(xw[kp][(ty + dy) * WHW + tx + dx],
                                         kk[dy * 3 + dx], aP);
#pragma unroll
      for (int o = 0; o < 16; ++o)
        accP[o] = __builtin_elementwise_fma(aP, pw[o], accP[o]);
    }
  }

  // ---- last chunk: stage + compute (no prefetch) ----
#pragma unroll
  for (int k = 0; k < KP; ++k)
    xw[k][i0] = __builtin_elementwise_fma(pf0[k], r0P, n0P);
  if (has1) {
#pragma unroll
    for (int k = 0; k < KP; ++k)
      xw[k][i1] = __builtin_elementwise_fma(pf1[k], r1P, n1P);
  }
  {
    int pc0 = pbase + (NCH - 1) * KP;
#pragma unroll
    for (int kp = 0; kp < KP; ++kp) {
      const f32x2* kk = kk2 + (size_t)(pc0 + kp) * 9;
      const f32x2* pw = pw2 + (size_t)(pc0 + kp) * 16;
      f32x2 aP = {0.f, 0.f};
#pragma unroll
      for (int dy = 0; dy < 3; ++dy)
#pragma unroll
        for (int dx = 0; dx < 3; ++dx)
          aP = __builtin_elementwise_fma(xw[kp][(ty + dy) * WHW + tx + dx],
                                         kk[dy * 3 + dx], aP);
#pragma unroll
      for (int o = 0; o < 16; ++o)
        accP[o] = __builtin_elementwise_fma(aP, pw[o], accP[o]);
    }
  }

  int hp = h0 + ty, wp = w0 + tx;
  if (hp < H_ && wp < W_) {
    int hw = hp * W_ + wp;
    float* dst = velA + (size_t)b * 16 * HW_ + hw;
#pragma unroll
    for (int o = 0; o < 16; ++o)
      unsafeAtomicAdd(&dst[(size_t)o * HW_], accP[o].x + accP[o].y);
  }
}

// ------------------------------------------------------------------
// k_samp: departure points + bicubic geo-sample + packed 1x1 up (8->384)
// ------------------------------------------------------------------
__device__ __forceinline__ void cubw(float t, float w[4]) {
  const float A = -0.75f;
  float t1 = t + 1.0f;
  w[0] = ((A * t1 - 5.0f * A) * t1 + 8.0f * A) * t1 - 4.0f * A;
  w[1] = ((A + 2.0f) * t - (A + 3.0f)) * t * t + 1.0f;
  float s = 1.0f - t;
  w[2] = ((A + 2.0f) * s - (A + 3.0f)) * s * s + 1.0f;
  float t2 = 2.0f - t;
  w[3] = ((A * t2 - 5.0f * A) * t2 + 8.0f * A) * t2 - 4.0f * A;
}

__global__ __launch_bounds__(256) void k_samp(
    const float* __restrict__ velA, const float* __restrict__ proj,
    const float* __restrict__ latg, const float* __restrict__ lonG,
    const float* __restrict__ dtp, const float* __restrict__ upT2,
    const float* __restrict__ up_b, const float* __restrict__ vbias,
    float* __restrict__ out) {
  int p = blockIdx.x * 256 + threadIdx.x;
  if (p >= NP_) return;
  int b = p / HW_, hw = p - b * HW_;

  const float TWO_PI = 6.28318530717958647692f;
  const float X_SCALE = 57.295779513082320877f;  // W/(2*pi)
  const float MIN_LAT = -1.57079632679489661923f;
  const float Y_SCALE = 57.295779513082320877f;  // (H-1)/pi

  float dt = dtp[0];
  float lat_p = latg[p];
  float lon_p = lonG[p];
  float sin_p, cos_p;
  sincosf(lat_p, &sin_p, &cos_p);

  f32x2 s2[V_];
  const float* projb = proj + (size_t)b * V_ * HW_;
  const float* vA = velA + (size_t)b * 16 * HW_ + hw;

  for (int vch = 0; vch < V_; ++vch) {
    float u  = vA[(size_t)vch * HW_] + vbias[vch];
    float vv = vA[(size_t)(8 + vch) * HW_] + vbias[8 + vch];
    float lon_pr = -u * dt;
    float lat_pr = -vv * dt;
    float s_lp, c_lp, s_op, c_op;
    sincosf(lat_pr, &s_lp, &c_lp);
    sincosf(lon_pr, &s_op, &c_op);
    float sin_lat = s_lp * cos_p + c_lp * c_op * sin_p;
    sin_lat = fminf(fmaxf(sin_lat, -1.0f + 1e-7f), 1.0f - 1e-7f);
    float lat_dep = asinf(sin_lat);
    float num = c_lp * s_op;
    float den = c_lp * c_op * cos_p - s_lp * sin_p;
    float lon_dep = fmodf(lon_p + atan2f(num, den) + TWO_PI, TWO_PI);

    float xf = fmaf(lon_dep, X_SCALE, 2.0f);            // pix_x + PAD
    float yf = fmaf(lat_dep - MIN_LAT, Y_SCALE, 2.0f);  // pix_y + PAD

    float x0f = floorf(xf), txf = xf - x0f;
    float y0f = floorf(yf), tyf = yf - y0f;
    int ix0 = (int)x0f, iy0 = (int)y0f;
    float wx[4], wy[4];
    cubw(txf, wx);
    cubw(tyf, wy);

    const float* pv = projb + (size_t)vch * HW_;
    float acc = 0.f;
#pragma unroll
    for (int i = 0; i < 4; ++i) {
      int yi = iy0 - 1 + i;
      yi = yi < 0 ? 0 : (yi > HP_ - 1 ? HP_ - 1 : yi);
      int hh = yi - 2;
      int hs, sh = 0;
      if (hh < 0)        { hs = -1 - hh;         sh = 1; }
      else if (hh >= H_) { hs = 2 * H_ - 1 - hh; sh = 1; }
      else               { hs = hh; }
      const float* row = pv + hs * W_;
      int shoff = sh ? 180 : 0;
      float r = 0.f;
#pragma unroll
      for (int j = 0; j < 4; ++j) {
        int xi = ix0 - 1 + j;
        xi = xi < 0 ? 0 : (xi > WP_ - 1 ? WP_ - 1 : xi);
        int ww = xi - 2 + shoff;
        ww = ((ww % W_) + W_) % W_;
        r = fmaf(row[ww], wx[j], r);
      }
      acc = fmaf(r, wy[i], acc);
    }
    s2[vch] = f32x2{acc, acc};  // proj already includes down_b
  }

  // packed up-conv: 2 output channels per iteration
  float* ob = out + (size_t)b * C_ * HW_ + hw;
  const f32x2* up2 = (const f32x2*)upT2;        // [pair*8 + v]
  const f32x2* ub2 = (const f32x2*)up_b;        // bias pairs
  for (int i = 0; i < C_ / 2; ++i) {
    f32x2 o2 = ub2[i];
    const f32x2* uw = up2 + (size_t)i * 8;
#pragma unroll
    for (int v = 0; v < V_; ++v) o2 = __builtin_elementwise_fma(s2[v], uw[v], o2);
    ob[(size_t)(2 * i) * HW_] = o2.x;
    ob[(size_t)(2 * i + 1) * HW_] = o2.y;
  }
}

// ------------------------------------------------------------------
extern "C" void kernel_launch(void* const* d_in, const int* in_sizes, int n_in,
                              void* d_out, int out_size, void* d_ws,
                              size_t ws_size, hipStream_t stream) {
  const float* hidden = (const float*)d_in[0];
  const float* latg   = (const float*)d_in[1];
  const float* lonG   = (const float*)d_in[2];
  const float* dtp    = (const float*)d_in[3];
  const float* nsc    = (const float*)d_in[4];
  const float* nbi    = (const float*)d_in[5];
  const float* dwk    = (const float*)d_in[6];
  const float* dwb    = (const float*)d_in[7];
  const float* pw_w   = (const float*)d_in[8];
  const float* pw_b   = (const float*)d_in[9];
  const float* down_w = (const float*)d_in[10];
  const float* down_b = (const float*)d_in[11];
  const float* up_w   = (const float*)d_in[12];
  const float* up_b   = (const float*)d_in[13];
  float* out = (float*)d_out;

  float* ws    = (float*)d_ws;
  float* meanv = ws;                       // NP_
  float* rstdv = ws + NP_;                 // NP_
  float* velA  = ws + 2 * (size_t)NP_;     // 16*NP_
  float* proj  = ws + 18 * (size_t)NP_;    // 8*NP_
  float* vbias = ws + 26 * (size_t)NP_;    // 16
  float* kswt2 = vbias + 16;               // 192*18
  float* pwT2  = kswt2 + 192 * 18;         // 192*32
  float* upT2  = pwT2 + 192 * 32;          // 192*16

  int nblk = (NP_ + 255) / 256;
  hipLaunchKernelGGL(k_prep, dim3(1), dim3(C_), 0, stream, nsc, nbi, dwk, dwb,
                     pw_w, pw_b, up_w, vbias, kswt2, pwT2, upT2);
  hipLaunchKernelGGL(k_stats, dim3(nblk), dim3(256), 0, stream, hidden, down_w,
                     down_b, meanv, rstdv, proj);
  hipMemsetAsync(velA, 0, (size_t)16 * NP_ * sizeof(float), stream);
  hipLaunchKernelGGL(k_vel, dim3(NWG_VEL), dim3(256), 0, stream, hidden, meanv,
                     rstdv, kswt2, pwT2, velA);
  hipLaunchKernelGGL(k_samp, dim3(nblk), dim3(256), 0, stream, velA, proj,
                     latg, lonG, dtp, upT2, up_b, vbias, out);
}